// Round 17
// baseline (119.747 us; speedup 1.0000x reference)
//
#include <hip/hip_runtime.h>

// Conv2d 3x3, cin=4, cout=4, pad=1, stride=1 on [4,4096,4096] fp32.
//
// Round-17: ci-PAIR fusion on the R14 skeleton (95.8 us best).
// Per block (512px x 8rows, thread = 4px x 4rows x 4cout):
//   stage pair0 (ci0,ci1: 20 chunks/wave->10 DMAs) + pair1 (10 more DMAs)
//   -> vmcnt(10) + barrier -> compute ci0,ci1 (~4600 issue-cy window)
//   -> vmcnt(0)  + barrier -> compute ci2,ci3 -> nt-store.
// Barriers/block: 7 -> 2; DMAs in flight/wave: 10 -> 20 (smoother HBM);
// no LDS buffer reuse within a block -> zero WAR hazards.
// LDS = 4 ci x 10 rows x 512 x 4B = 81920 B (dynamic, >64KB static limit)
// -> 2 blocks/CU (160 KiB budget). Grid stays 4096 fine-grained (R16
// lesson: coarse persistent blocks break neighbor-block L2/L3 reuse).

#define IW 4096
#define IH 4096
constexpr long long HWsz = (long long)IH * IW;

typedef float v4f __attribute__((ext_vector_type(4)));

__device__ __forceinline__ void gload_lds16(const float* g, float* l) {
    __builtin_amdgcn_global_load_lds(
        (const __attribute__((address_space(1))) char*)g,
        (__attribute__((address_space(3))) char*)l, 16, 0, 0);
}

// stage one ci-PAIR q: 2 planes x 10 rows x 2 half-strips = 40 chunks;
// wave w owns chunks 10w..10w+9 (10 DMAs, vmcnt-counted)
__device__ __forceinline__ void stage_pair(const float* __restrict__ xin,
                                           int q, float* smem,
                                           int y0, int X0, int w, int l) {
    #pragma unroll
    for (int k = 0; k < 10; ++k) {
        const int c   = 10 * w + k;              // chunk id 0..39 (uniform)
        const int ciq = (c >= 20) ? 1 : 0;       // plane within pair
        const int cc  = c - 20 * ciq;
        const int rr  = cc >> 1;                 // staged row 0..9
        const int h   = cc & 1;                  // half-strip
        const int ci  = 2 * q + ciq;
        const float* plane = xin + (long long)ci * HWsz;
        int yy = y0 - 1 + rr;
        int yc = yy < 0 ? 0 : (yy >= IH ? IH - 1 : yy);   // clamp: pad rows
        float* dst = smem + ((2 * q + ciq) * 10 + rr) * 512 + 256 * h;
        gload_lds16(plane + (long long)yc * IW + (X0 + 256 * h + 4 * l), dst);
    }
}

__device__ __forceinline__ void compute_ci(float acc[4][4][4],
                                           const float (*rbuf)[512],
                                           const float* __restrict__ xin,
                                           const float* __restrict__ wt,
                                           int ci, int y0, int X0,
                                           int p_u, int tx) {
    const float* plane = xin + (long long)ci * HWsz;
    #pragma unroll
    for (int dy = 0; dy < 6; ++dy) {
        const int r  = 4 * p_u + dy;             // staged row (wave-uniform)
        const int yy = y0 - 1 + r;               // global input row (uniform)
        if (yy >= 0 && yy < IH) {                // wave-uniform row skip
            // wave-uniform halo addresses -> scalar loads
            const float hL = (X0 > 0)
                ? plane[(long long)yy * IW + X0 - 1]   : 0.f;
            const float hR = (X0 + 512 < IW)
                ? plane[(long long)yy * IW + X0 + 512] : 0.f;
            const v4f a = *reinterpret_cast<const v4f*>(&rbuf[r][4 * tx]);
            const float L = (tx == 0)   ? hL : rbuf[r][4 * tx - 1];
            const float R = (tx == 127) ? hR : rbuf[r][4 * tx + 4];
            float vv[6] = {L, a.x, a.y, a.z, a.w, R};
            #pragma unroll
            for (int rk = 0; rk < 3; ++rk) {
                const int o = dy - rk;           // output row offset in pair
                if (o >= 0 && o < 4) {
                    #pragma unroll
                    for (int co = 0; co < 4; ++co) {
                        #pragma unroll
                        for (int kx = 0; kx < 3; ++kx) {
                            const float w = wt[((co * 4 + ci) * 3 + rk) * 3 + kx];
                            #pragma unroll
                            for (int p = 0; p < 4; ++p)
                                acc[o][co][p] = fmaf(w, vv[p + kx], acc[o][co][p]);
                        }
                    }
                }
            }
        }
    }
}

__global__ __launch_bounds__(256) void conv3x3_kernel(
    const float* __restrict__ xin,   // [4][4096][4096]
    const float* __restrict__ wt,    // [4][4][3][3]
    float* __restrict__ out)         // [4][4096][4096]
{
    extern __shared__ __align__(16) float smem[];   // 81920 B: [4][10][512]

    // grid 4096 = 512 row-blocks x 8 x-strips; bijective XCD swizzle
    const int bid = blockIdx.x;
    const int swz = (bid & 7) * 512 + (bid >> 3);
    const int rowblk = swz >> 3;                  // 0..511
    const int xs     = swz & 7;                   // 0..7
    const int y0     = rowblk << 3;               // 8 output rows
    const int X0     = xs << 9;                   // 512-px strip
    const int t      = (int)threadIdx.x;
    const int w      = t >> 6, l = t & 63;
    const int tx     = t & 127;                   // px index within pair
    const int p_u    = __builtin_amdgcn_readfirstlane(t >> 7);  // pair 0/1

    float acc[4][4][4];                           // [orow][cout][px]
    #pragma unroll
    for (int o = 0; o < 4; ++o)
        #pragma unroll
        for (int co = 0; co < 4; ++co)
            #pragma unroll
            for (int p = 0; p < 4; ++p) acc[o][co][p] = 0.f;

    // issue ALL staging upfront: 20 DMAs/wave (80 KB/block in flight)
    stage_pair(xin, 0, smem, y0, X0, w, l);
    stage_pair(xin, 1, smem, y0, X0, w, l);

    // wait my oldest 10 (= pair0); pair1's 10 stay in flight
    asm volatile("s_waitcnt vmcnt(10)\n\ts_barrier" ::: "memory");
    compute_ci(acc, reinterpret_cast<const float (*)[512]>(smem + 0 * 5120),
               xin, wt, 0, y0, X0, p_u, tx);
    compute_ci(acc, reinterpret_cast<const float (*)[512]>(smem + 1 * 5120),
               xin, wt, 1, y0, X0, p_u, tx);

    asm volatile("s_waitcnt vmcnt(0)\n\ts_barrier" ::: "memory");
    compute_ci(acc, reinterpret_cast<const float (*)[512]>(smem + 2 * 5120),
               xin, wt, 2, y0, X0, p_u, tx);
    compute_ci(acc, reinterpret_cast<const float (*)[512]>(smem + 3 * 5120),
               xin, wt, 3, y0, X0, p_u, tx);

    const int x0g = X0 + 4 * tx;
    #pragma unroll
    for (int o = 0; o < 4; ++o) {
        const long long obase = (long long)(y0 + 4 * p_u + o) * IW + x0g;
        #pragma unroll
        for (int co = 0; co < 4; ++co) {
            v4f ov;
            ov.x = acc[o][co][0]; ov.y = acc[o][co][1];
            ov.z = acc[o][co][2]; ov.w = acc[o][co][3];
            __builtin_nontemporal_store(ov,
                reinterpret_cast<v4f*>(out + co * HWsz + obase));
        }
    }
}

extern "C" void kernel_launch(void* const* d_in, const int* in_sizes, int n_in,
                              void* d_out, int out_size, void* d_ws, size_t ws_size,
                              hipStream_t stream) {
    const float* xin = (const float*)d_in[0];
    const float* wt  = (const float*)d_in[1];
    float* out       = (float*)d_out;

    // allow >64KB dynamic LDS (host-side, deterministic, capture-safe)
    static_assert(sizeof(float) == 4, "");
    hipFuncSetAttribute(reinterpret_cast<const void*>(conv3x3_kernel),
                        hipFuncAttributeMaxDynamicSharedMemorySize, 81920);

    dim3 grid(4096), block(256);
    hipLaunchKernelGGL(conv3x3_kernel, grid, block, 81920, stream,
                       xin, wt, out);
}

// Round 18
// 90.336 us; speedup vs baseline: 1.3256x; 1.3256x over previous
//
#include <hip/hip_runtime.h>

// Conv2d 3x3, cin=4, cout=4, pad=1, stride=1 on [4,4096,4096] fp32.
//
// Round-18 = round-14 (95.8 us best: 512px x 8rows, 40960 B LDS = exactly
// 4 blocks/CU, vmcnt(5) DMA pipeline, XCD swizzle, nt stores) with ONE
// change: the 48 L/R halo loads (4 ci x 6 dy x 2 sides, wave-uniform
// addresses) are HOISTED to kernel start instead of JIT inside compute_ci.
// They are provably uniform (blockIdx-derived + readfirstlane'd pair id)
// -> s_load into SGPRs, latency hidden under the prologue DMA wait. The
// ci loop is fully unrolled so hl[ci][dy]/hr[ci][dy] stay compile-time
// indexed (rule #20: no runtime-indexed register arrays).

#define IW 4096
#define IH 4096
constexpr long long HWsz = (long long)IH * IW;

typedef float v4f __attribute__((ext_vector_type(4)));

__device__ __forceinline__ void gload_lds16(const float* g, float* l) {
    __builtin_amdgcn_global_load_lds(
        (const __attribute__((address_space(1))) char*)g,
        (__attribute__((address_space(3))) char*)l, 16, 0, 0);
}

// stage one ci plane: 10 rows x 2 half-rows = 20 chunks; wave w -> 5w..5w+4
__device__ __forceinline__ void stage(const float* __restrict__ xin, int ci,
                                      float (*rbuf)[512], int y0, int X0,
                                      int w, int l) {
    const float* plane = xin + (long long)ci * HWsz;
    #pragma unroll
    for (int k = 0; k < 5; ++k) {
        const int c = 5 * w + k;                 // chunk id (wave-uniform)
        const int r = c >> 1;                    // staged row 0..9
        const int h = c & 1;                     // half-strip
        int yy = y0 - 1 + r;
        int yc = yy < 0 ? 0 : (yy >= IH ? IH - 1 : yy);   // clamp: pad rows
        gload_lds16(plane + (long long)yc * IW + (X0 + 256 * h + 4 * l),
                    &rbuf[r][256 * h]);
    }
}

// compute one ci plane; halos come from pre-hoisted registers hl[6]/hr[6]
__device__ __forceinline__ void compute_ci(float acc[4][4][4],
                                           const float (*rbuf)[512],
                                           const float hl[6], const float hr[6],
                                           const float* __restrict__ wt,
                                           int ci, int y0, int p_u, int tx) {
    #pragma unroll
    for (int dy = 0; dy < 6; ++dy) {
        const int r  = 4 * p_u + dy;             // staged row (wave-uniform)
        const int yy = y0 - 1 + r;               // global input row (uniform)
        if (yy >= 0 && yy < IH) {                // wave-uniform row skip
            const v4f a = *reinterpret_cast<const v4f*>(&rbuf[r][4 * tx]);
            const float L = (tx == 0)   ? hl[dy] : rbuf[r][4 * tx - 1];
            const float R = (tx == 127) ? hr[dy] : rbuf[r][4 * tx + 4];
            float vv[6] = {L, a.x, a.y, a.z, a.w, R};
            #pragma unroll
            for (int rk = 0; rk < 3; ++rk) {
                const int o = dy - rk;           // output row offset in pair
                if (o >= 0 && o < 4) {
                    #pragma unroll
                    for (int co = 0; co < 4; ++co) {
                        #pragma unroll
                        for (int kx = 0; kx < 3; ++kx) {
                            const float w = wt[((co * 4 + ci) * 3 + rk) * 3 + kx];
                            #pragma unroll
                            for (int p = 0; p < 4; ++p)
                                acc[o][co][p] = fmaf(w, vv[p + kx], acc[o][co][p]);
                        }
                    }
                }
            }
        }
    }
}

__global__ __launch_bounds__(256) void conv3x3_kernel(
    const float* __restrict__ xin,   // [4][4096][4096]
    const float* __restrict__ wt,    // [4][4][3][3]
    float* __restrict__ out)         // [4][4096][4096]
{
    __shared__ __align__(16) float rows[2][10][512];   // 40960 B exactly

    // grid 4096 = 512 row-blocks x 8 x-strips; bijective XCD swizzle
    const int bid = blockIdx.x;
    const int swz = (bid & 7) * 512 + (bid >> 3);
    const int rowblk = swz >> 3;                  // 0..511
    const int xs     = swz & 7;                   // 0..7
    const int y0     = rowblk << 3;               // 8 output rows
    const int X0     = xs << 9;                   // 512-px strip
    const int t      = (int)threadIdx.x;
    const int w      = t >> 6, l = t & 63;
    const int tx     = t & 127;                   // px index within pair
    const int p_u    = __builtin_amdgcn_readfirstlane(t >> 7);  // pair 0/1

    // ---- hoisted halo loads: uniform addresses -> scalar loads, issued
    //      before the prologue DMA so latency hides under the first wait ----
    float hl[4][6], hr[4][6];
    #pragma unroll
    for (int ci = 0; ci < 4; ++ci) {
        const float* plane = xin + (long long)ci * HWsz;
        #pragma unroll
        for (int dy = 0; dy < 6; ++dy) {
            const int yy = y0 - 1 + 4 * p_u + dy;
            const bool vrow = (yy >= 0 && yy < IH);
            const long long rb = (long long)(vrow ? yy : 0) * IW;
            hl[ci][dy] = (vrow && X0 > 0)        ? plane[rb + X0 - 1]   : 0.f;
            hr[ci][dy] = (vrow && X0 + 512 < IW) ? plane[rb + X0 + 512] : 0.f;
        }
    }

    float acc[4][4][4];                           // [orow][cout][px]
    #pragma unroll
    for (int o = 0; o < 4; ++o)
        #pragma unroll
        for (int co = 0; co < 4; ++co)
            #pragma unroll
            for (int p = 0; p < 4; ++p) acc[o][co][p] = 0.f;

    // ---- fully unrolled 2-phase pipeline (compile-time ci) ----
    stage(xin, 0, rows[0], y0, X0, w, l);         // prologue

    // ci = 0
    stage(xin, 1, rows[1], y0, X0, w, l);
    asm volatile("s_waitcnt vmcnt(5)\n\ts_barrier" ::: "memory");
    compute_ci(acc, rows[0], hl[0], hr[0], wt, 0, y0, p_u, tx);
    asm volatile("s_barrier" ::: "memory");
    // ci = 1
    stage(xin, 2, rows[0], y0, X0, w, l);
    asm volatile("s_waitcnt vmcnt(5)\n\ts_barrier" ::: "memory");
    compute_ci(acc, rows[1], hl[1], hr[1], wt, 1, y0, p_u, tx);
    asm volatile("s_barrier" ::: "memory");
    // ci = 2
    stage(xin, 3, rows[1], y0, X0, w, l);
    asm volatile("s_waitcnt vmcnt(5)\n\ts_barrier" ::: "memory");
    compute_ci(acc, rows[0], hl[2], hr[2], wt, 2, y0, p_u, tx);
    asm volatile("s_barrier" ::: "memory");
    // ci = 3
    asm volatile("s_waitcnt vmcnt(0)\n\ts_barrier" ::: "memory");
    compute_ci(acc, rows[1], hl[3], hr[3], wt, 3, y0, p_u, tx);

    const int x0g = X0 + 4 * tx;
    #pragma unroll
    for (int o = 0; o < 4; ++o) {
        const long long obase = (long long)(y0 + 4 * p_u + o) * IW + x0g;
        #pragma unroll
        for (int co = 0; co < 4; ++co) {
            v4f ov;
            ov.x = acc[o][co][0]; ov.y = acc[o][co][1];
            ov.z = acc[o][co][2]; ov.w = acc[o][co][3];
            __builtin_nontemporal_store(ov,
                reinterpret_cast<v4f*>(out + co * HWsz + obase));
        }
    }
}

extern "C" void kernel_launch(void* const* d_in, const int* in_sizes, int n_in,
                              void* d_out, int out_size, void* d_ws, size_t ws_size,
                              hipStream_t stream) {
    const float* xin = (const float*)d_in[0];
    const float* wt  = (const float*)d_in[1];
    float* out       = (float*)d_out;

    dim3 grid(4096), block(256);
    hipLaunchKernelGGL(conv3x3_kernel, grid, block, 0, stream, xin, wt, out);
}